// Round 1
// baseline (870.650 us; speedup 1.0000x reference)
//
#include <hip/hip_runtime.h>
#include <hip/hip_bf16.h>

#define NN 100000
#define NE 1600000
#define NG 128
#define FIN 128
#define HID 32
#define NCLS 10

#define SCAN_B 1024
#define NB ((NN + SCAN_B - 1) / SCAN_B)   // 98

// ---------------- init: zero accumulators ----------------
__global__ void k_init(int* __restrict__ counts, float* __restrict__ gsum,
                       float* __restrict__ gcnt) {
    int i = blockIdx.x * blockDim.x + threadIdx.x;
    int stride = gridDim.x * blockDim.x;
    for (int j = i; j < NN; j += stride) counts[j] = 0;
    for (int j = i; j < NG * HID; j += stride) gsum[j] = 0.f;
    for (int j = i; j < NG; j += stride) gcnt[j] = 0.f;
}

// ---------------- degree histogram over dst ----------------
__global__ void k_hist(const int* __restrict__ dst, int* __restrict__ counts) {
    int i = blockIdx.x * blockDim.x + threadIdx.x;
    int stride = gridDim.x * blockDim.x;
    for (int e = i; e < NE; e += stride) atomicAdd(&counts[dst[e]], 1);
}

// ---------------- dinv = rsqrt(deg + 1 self loop) ----------------
__global__ void k_dinv(const int* __restrict__ counts, float* __restrict__ dinv) {
    int i = blockIdx.x * blockDim.x + threadIdx.x;
    if (i < NN) dinv[i] = rsqrtf((float)counts[i] + 1.0f);
}

// ---------------- scan phase A: per-block exclusive scan ----------------
__global__ void k_scanA(const int* __restrict__ counts, int* __restrict__ row_ptr,
                        int* __restrict__ bsum) {
    __shared__ int lds[SCAN_B];
    int i = blockIdx.x * SCAN_B + threadIdx.x;
    int v = (i < NN) ? counts[i] : 0;
    lds[threadIdx.x] = v;
    __syncthreads();
    int val = v;
    for (int off = 1; off < SCAN_B; off <<= 1) {
        int u = 0;
        if ((int)threadIdx.x >= off) u = lds[threadIdx.x - off];
        __syncthreads();
        if ((int)threadIdx.x >= off) { val += u; lds[threadIdx.x] = val; }
        __syncthreads();
    }
    if (i < NN) row_ptr[i] = val - v;            // exclusive within block
    if (threadIdx.x == SCAN_B - 1) bsum[blockIdx.x] = val;  // block total
}

// ---------------- scan phase B: scan block sums (single block) ----------------
__global__ void k_scanB(int* __restrict__ bsum) {
    __shared__ int lds[128];
    int t = threadIdx.x;
    int v = (t < NB) ? bsum[t] : 0;
    lds[t] = v;
    __syncthreads();
    int val = v;
    for (int off = 1; off < 128; off <<= 1) {
        int u = 0;
        if (t >= off) u = lds[t - off];
        __syncthreads();
        if (t >= off) { val += u; lds[t] = val; }
        __syncthreads();
    }
    if (t < NB) bsum[t] = val - v;               // exclusive
}

// ---------------- scan phase C: add offsets, init cursor ----------------
__global__ void k_scanC(int* __restrict__ row_ptr, int* __restrict__ cursor,
                        const int* __restrict__ bsum) {
    int i = blockIdx.x * SCAN_B + threadIdx.x;
    if (i < NN) {
        int r = row_ptr[i] + bsum[blockIdx.x];
        row_ptr[i] = r;
        cursor[i] = r;
    }
    if (i == 0) row_ptr[NN] = NE;
}

// ---------------- scatter edges into CSR slots ----------------
__global__ void k_scatter(const int* __restrict__ src, const int* __restrict__ dst,
                          int* __restrict__ cursor, int* __restrict__ csr_src) {
    int i = blockIdx.x * blockDim.x + threadIdx.x;
    int stride = gridDim.x * blockDim.x;
    for (int e = i; e < NE; e += stride) {
        int d = dst[e];
        int p = atomicAdd(&cursor[d], 1);
        csr_src[p] = src[e];
    }
}

// ---------------- layer-0 GEMM: t = (x @ W0) * dinv ----------------
__global__ void k_gemm0(const float* __restrict__ x, const float* __restrict__ W,
                        const float* __restrict__ dinv, float* __restrict__ t) {
    __shared__ float Ws[FIN * HID];
    for (int j = threadIdx.x; j < FIN * HID; j += 256) Ws[j] = W[j];
    __syncthreads();
    int gid = blockIdx.x * 256 + threadIdx.x;
    int i = gid >> 5, f = gid & 31;
    if (i >= NN) return;
    const float4* xr = (const float4*)(x + (size_t)i * FIN);
    float acc = 0.f;
#pragma unroll
    for (int k4 = 0; k4 < FIN / 4; k4++) {
        float4 xv = xr[k4];
        int kb = k4 * 4;
        acc = fmaf(xv.x, Ws[(kb + 0) * HID + f], acc);
        acc = fmaf(xv.y, Ws[(kb + 1) * HID + f], acc);
        acc = fmaf(xv.z, Ws[(kb + 2) * HID + f], acc);
        acc = fmaf(xv.w, Ws[(kb + 3) * HID + f], acc);
    }
    t[(size_t)i * HID + f] = acc * dinv[i];
}

// ---------------- hidden GEMM: t = (h @ W) * dinv ----------------
__global__ void k_gemmh(const float* __restrict__ h, const float* __restrict__ W,
                        const float* __restrict__ dinv, float* __restrict__ t) {
    __shared__ float Ws[HID * HID];
    for (int j = threadIdx.x; j < HID * HID; j += 256) Ws[j] = W[j];
    __syncthreads();
    int gid = blockIdx.x * 256 + threadIdx.x;
    int i = gid >> 5, f = gid & 31;
    if (i >= NN) return;
    const float4* hr = (const float4*)(h + (size_t)i * HID);
    float acc = 0.f;
#pragma unroll
    for (int k4 = 0; k4 < HID / 4; k4++) {
        float4 hv = hr[k4];
        int kb = k4 * 4;
        acc = fmaf(hv.x, Ws[(kb + 0) * HID + f], acc);
        acc = fmaf(hv.y, Ws[(kb + 1) * HID + f], acc);
        acc = fmaf(hv.z, Ws[(kb + 2) * HID + f], acc);
        acc = fmaf(hv.w, Ws[(kb + 3) * HID + f], acc);
    }
    t[(size_t)i * HID + f] = acc * dinv[i];
}

// ---------------- aggregation: h_out[i] = relu(dinv[i]*(sum t[src] + t[i]) + b) ----------------
__global__ void k_agg(const float* __restrict__ t, const int* __restrict__ row_ptr,
                      const int* __restrict__ csr_src, const float* __restrict__ dinv,
                      const float* __restrict__ b, float* __restrict__ hout) {
    int idx = blockIdx.x * blockDim.x + threadIdx.x;
    int i = idx >> 3;                 // node
    int l = (idx & 7) * 4;            // feature offset (float4 lane)
    if (i >= NN) return;
    float4 acc = *(const float4*)&t[(size_t)i * HID + l];   // self term t'[i]
    int beg = row_ptr[i], end = row_ptr[i + 1];
    for (int e = beg; e < end; e++) {
        int s = csr_src[e];
        const float4 v = *(const float4*)&t[(size_t)s * HID + l];
        acc.x += v.x; acc.y += v.y; acc.z += v.z; acc.w += v.w;
    }
    float di = dinv[i];
    float4 r;
    r.x = fmaxf(fmaf(acc.x, di, b[l + 0]), 0.f);
    r.y = fmaxf(fmaf(acc.y, di, b[l + 1]), 0.f);
    r.z = fmaxf(fmaf(acc.z, di, b[l + 2]), 0.f);
    r.w = fmaxf(fmaf(acc.w, di, b[l + 3]), 0.f);
    *(float4*)&hout[(size_t)i * HID + l] = r;
}

// ---------------- pooling: per-graph sums + counts ----------------
__global__ void k_pool(const float* __restrict__ h, const int* __restrict__ batch,
                       float* __restrict__ gsum, float* __restrict__ gcnt) {
    int idx = blockIdx.x * blockDim.x + threadIdx.x;
    int i = idx >> 3;
    int l = (idx & 7) * 4;
    if (i >= NN) return;
    int g = batch[i];
    const float4 v = *(const float4*)&h[(size_t)i * HID + l];
    atomicAdd(&gsum[g * HID + l + 0], v.x);
    atomicAdd(&gsum[g * HID + l + 1], v.y);
    atomicAdd(&gsum[g * HID + l + 2], v.z);
    atomicAdd(&gsum[g * HID + l + 3], v.w);
    if (l == 0) atomicAdd(&gcnt[g], 1.0f);
}

// ---------------- classifier + log_softmax ----------------
__global__ void k_classify(const float* __restrict__ gsum, const float* __restrict__ gcnt,
                           const float* __restrict__ Wl, const float* __restrict__ bl,
                           float* __restrict__ out) {
    __shared__ float w[HID * NCLS];
    __shared__ float bb[NCLS];
    int t = threadIdx.x;
    for (int j = t; j < HID * NCLS; j += blockDim.x) w[j] = Wl[j];
    if (t < NCLS) bb[t] = bl[t];
    __syncthreads();
    if (t >= NG) return;
    float c = gcnt[t];
    c = c > 1.f ? c : 1.f;
    float p[HID];
#pragma unroll
    for (int k = 0; k < HID; k++) p[k] = gsum[t * HID + k] / c;
    float lg[NCLS];
    float m = -1e30f;
#pragma unroll
    for (int c2 = 0; c2 < NCLS; c2++) {
        float a = bb[c2];
#pragma unroll
        for (int k = 0; k < HID; k++) a = fmaf(p[k], w[k * NCLS + c2], a);
        a = a > 0.f ? a : 0.f;
        lg[c2] = a;
        m = fmaxf(m, a);
    }
    float s = 0.f;
#pragma unroll
    for (int c2 = 0; c2 < NCLS; c2++) s += expf(lg[c2] - m);
    float ls = logf(s);
#pragma unroll
    for (int c2 = 0; c2 < NCLS; c2++) out[t * NCLS + c2] = lg[c2] - m - ls;
}

extern "C" void kernel_launch(void* const* d_in, const int* in_sizes, int n_in,
                              void* d_out, int out_size, void* d_ws, size_t ws_size,
                              hipStream_t stream) {
    const float* x  = (const float*)d_in[0];
    const int* ei   = (const int*)d_in[1];      // [2, E] int32
    const int* batch = (const int*)d_in[2];
    const float* W0 = (const float*)d_in[3];
    const float* b0 = (const float*)d_in[4];
    const float* W1 = (const float*)d_in[5];
    const float* b1 = (const float*)d_in[6];
    const float* W2 = (const float*)d_in[7];
    const float* b2 = (const float*)d_in[8];
    const float* Wl = (const float*)d_in[9];
    const float* bl = (const float*)d_in[10];
    float* out = (float*)d_out;

    const int* esrc = ei;
    const int* edst = ei + NE;

    // bump allocator over workspace
    char* ws = (char*)d_ws;
    size_t off = 0;
    auto alloc = [&](size_t bytes) -> void* {
        void* p = ws + off;
        off = (off + bytes + 511) & ~(size_t)511;
        return p;
    };
    int*   counts  = (int*)alloc(NN * sizeof(int));
    int*   row_ptr = (int*)alloc((NN + 1) * sizeof(int));
    int*   cursor  = (int*)alloc(NN * sizeof(int));
    float* dinv    = (float*)alloc(NN * sizeof(float));
    int*   bsum    = (int*)alloc(256 * sizeof(int));
    int*   csr_src = (int*)alloc(NE * sizeof(int));
    float* tbuf    = (float*)alloc((size_t)NN * HID * sizeof(float));
    float* hA      = (float*)alloc((size_t)NN * HID * sizeof(float));
    float* hB      = (float*)alloc((size_t)NN * HID * sizeof(float));
    float* gsum    = (float*)alloc(NG * HID * sizeof(float));
    float* gcnt    = (float*)alloc(NG * sizeof(float));
    (void)ws_size; (void)in_sizes; (void)n_in; (void)out_size;

    // ---- CSR build ----
    k_init<<<256, 256, 0, stream>>>(counts, gsum, gcnt);
    k_hist<<<2048, 256, 0, stream>>>(edst, counts);
    k_dinv<<<(NN + 255) / 256, 256, 0, stream>>>(counts, dinv);
    k_scanA<<<NB, SCAN_B, 0, stream>>>(counts, row_ptr, bsum);
    k_scanB<<<1, 128, 0, stream>>>(bsum);
    k_scanC<<<NB, SCAN_B, 0, stream>>>(row_ptr, cursor, bsum);
    k_scatter<<<2048, 256, 0, stream>>>(esrc, edst, cursor, csr_src);

    const int gemm0_grid = (NN * HID + 255) / 256;
    const int agg_grid = (NN * 8 + 255) / 256;

    // ---- layer 0 ----
    k_gemm0<<<gemm0_grid, 256, 0, stream>>>(x, W0, dinv, tbuf);
    k_agg<<<agg_grid, 256, 0, stream>>>(tbuf, row_ptr, csr_src, dinv, b0, hA);
    // ---- layer 1 ----
    k_gemmh<<<gemm0_grid, 256, 0, stream>>>(hA, W1, dinv, tbuf);
    k_agg<<<agg_grid, 256, 0, stream>>>(tbuf, row_ptr, csr_src, dinv, b1, hB);
    // ---- layer 2 ----
    k_gemmh<<<gemm0_grid, 256, 0, stream>>>(hB, W2, dinv, tbuf);
    k_agg<<<agg_grid, 256, 0, stream>>>(tbuf, row_ptr, csr_src, dinv, b2, hA);

    // ---- pooling + classifier ----
    k_pool<<<agg_grid, 256, 0, stream>>>(hA, batch, gsum, gcnt);
    k_classify<<<1, 128, 0, stream>>>(gsum, gcnt, Wl, bl, out);
}

// Round 2
// 442.108 us; speedup vs baseline: 1.9693x; 1.9693x over previous
//
#include <hip/hip_runtime.h>
#include <hip/hip_bf16.h>

#define NN 100000
#define NE 1600000
#define NG 128
#define FIN 128
#define HID 32
#define NCLS 10

#define SCAN_B 1024
#define NB ((NN + SCAN_B - 1) / SCAN_B)   // 98

#define POOL_CHUNK 512
#define POOL_SEG 16
#define POOL_NSEG (POOL_CHUNK / POOL_SEG)   // 32 segments/block
#define POOL_GSPAN 32
#define POOL_GRID ((NN + POOL_CHUNK - 1) / POOL_CHUNK)

// ---------------- init: zero accumulators ----------------
__global__ void k_init(int* __restrict__ counts, float* __restrict__ gsum,
                       float* __restrict__ gcnt) {
    int i = blockIdx.x * blockDim.x + threadIdx.x;
    int stride = gridDim.x * blockDim.x;
    for (int j = i; j < NN; j += stride) counts[j] = 0;
    for (int j = i; j < NG * HID; j += stride) gsum[j] = 0.f;
    for (int j = i; j < NG; j += stride) gcnt[j] = 0.f;
}

// ---------------- degree histogram over dst ----------------
__global__ void k_hist(const int* __restrict__ dst, int* __restrict__ counts) {
    int i = blockIdx.x * blockDim.x + threadIdx.x;
    int stride = gridDim.x * blockDim.x;
    for (int e = i; e < NE; e += stride) atomicAdd(&counts[dst[e]], 1);
}

// ---------------- dinv = rsqrt(deg + 1 self loop) ----------------
__global__ void k_dinv(const int* __restrict__ counts, float* __restrict__ dinv) {
    int i = blockIdx.x * blockDim.x + threadIdx.x;
    if (i < NN) dinv[i] = rsqrtf((float)counts[i] + 1.0f);
}

// ---------------- scan phase A: per-block exclusive scan ----------------
__global__ void k_scanA(const int* __restrict__ counts, int* __restrict__ row_ptr,
                        int* __restrict__ bsum) {
    __shared__ int lds[SCAN_B];
    int i = blockIdx.x * SCAN_B + threadIdx.x;
    int v = (i < NN) ? counts[i] : 0;
    lds[threadIdx.x] = v;
    __syncthreads();
    int val = v;
    for (int off = 1; off < SCAN_B; off <<= 1) {
        int u = 0;
        if ((int)threadIdx.x >= off) u = lds[threadIdx.x - off];
        __syncthreads();
        if ((int)threadIdx.x >= off) { val += u; lds[threadIdx.x] = val; }
        __syncthreads();
    }
    if (i < NN) row_ptr[i] = val - v;            // exclusive within block
    if (threadIdx.x == SCAN_B - 1) bsum[blockIdx.x] = val;  // block total
}

// ---------------- scan phase B: scan block sums (single block) ----------------
__global__ void k_scanB(int* __restrict__ bsum) {
    __shared__ int lds[128];
    int t = threadIdx.x;
    int v = (t < NB) ? bsum[t] : 0;
    lds[t] = v;
    __syncthreads();
    int val = v;
    for (int off = 1; off < 128; off <<= 1) {
        int u = 0;
        if (t >= off) u = lds[t - off];
        __syncthreads();
        if (t >= off) { val += u; lds[t] = val; }
        __syncthreads();
    }
    if (t < NB) bsum[t] = val - v;               // exclusive
}

// ---------------- scan phase C: add offsets, init cursor ----------------
__global__ void k_scanC(int* __restrict__ row_ptr, int* __restrict__ cursor,
                        const int* __restrict__ bsum) {
    int i = blockIdx.x * SCAN_B + threadIdx.x;
    if (i < NN) {
        int r = row_ptr[i] + bsum[blockIdx.x];
        row_ptr[i] = r;
        cursor[i] = r;
    }
    if (i == 0) row_ptr[NN] = NE;
}

// ---------------- scatter edges into CSR slots ----------------
__global__ void k_scatter(const int* __restrict__ src, const int* __restrict__ dst,
                          int* __restrict__ cursor, int* __restrict__ csr_src) {
    int i = blockIdx.x * blockDim.x + threadIdx.x;
    int stride = gridDim.x * blockDim.x;
    for (int e = i; e < NE; e += stride) {
        int d = dst[e];
        int p = atomicAdd(&cursor[d], 1);
        csr_src[p] = src[e];
    }
}

// ---------------- layer-0 GEMM: t = (x @ W0) * dinv ----------------
__global__ void k_gemm0(const float* __restrict__ x, const float* __restrict__ W,
                        const float* __restrict__ dinv, float* __restrict__ t) {
    __shared__ float Ws[FIN * HID];
    for (int j = threadIdx.x; j < FIN * HID; j += 256) Ws[j] = W[j];
    __syncthreads();
    int gid = blockIdx.x * 256 + threadIdx.x;
    int i = gid >> 5, f = gid & 31;
    if (i >= NN) return;
    const float4* xr = (const float4*)(x + (size_t)i * FIN);
    float acc = 0.f;
#pragma unroll
    for (int k4 = 0; k4 < FIN / 4; k4++) {
        float4 xv = xr[k4];
        int kb = k4 * 4;
        acc = fmaf(xv.x, Ws[(kb + 0) * HID + f], acc);
        acc = fmaf(xv.y, Ws[(kb + 1) * HID + f], acc);
        acc = fmaf(xv.z, Ws[(kb + 2) * HID + f], acc);
        acc = fmaf(xv.w, Ws[(kb + 3) * HID + f], acc);
    }
    t[(size_t)i * HID + f] = acc * dinv[i];
}

// ---------------- hidden GEMM: t = (h @ W) * dinv ----------------
__global__ void k_gemmh(const float* __restrict__ h, const float* __restrict__ W,
                        const float* __restrict__ dinv, float* __restrict__ t) {
    __shared__ float Ws[HID * HID];
    for (int j = threadIdx.x; j < HID * HID; j += 256) Ws[j] = W[j];
    __syncthreads();
    int gid = blockIdx.x * 256 + threadIdx.x;
    int i = gid >> 5, f = gid & 31;
    if (i >= NN) return;
    const float4* hr = (const float4*)(h + (size_t)i * HID);
    float acc = 0.f;
#pragma unroll
    for (int k4 = 0; k4 < HID / 4; k4++) {
        float4 hv = hr[k4];
        int kb = k4 * 4;
        acc = fmaf(hv.x, Ws[(kb + 0) * HID + f], acc);
        acc = fmaf(hv.y, Ws[(kb + 1) * HID + f], acc);
        acc = fmaf(hv.z, Ws[(kb + 2) * HID + f], acc);
        acc = fmaf(hv.w, Ws[(kb + 3) * HID + f], acc);
    }
    t[(size_t)i * HID + f] = acc * dinv[i];
}

// ---------------- aggregation: h_out[i] = relu(dinv[i]*(sum t[src] + t[i]) + b) ----------------
__global__ void k_agg(const float* __restrict__ t, const int* __restrict__ row_ptr,
                      const int* __restrict__ csr_src, const float* __restrict__ dinv,
                      const float* __restrict__ b, float* __restrict__ hout) {
    int idx = blockIdx.x * blockDim.x + threadIdx.x;
    int i = idx >> 3;                 // node
    int l = (idx & 7) * 4;            // feature offset (float4 lane)
    if (i >= NN) return;
    float4 acc = *(const float4*)&t[(size_t)i * HID + l];   // self term t'[i]
    int beg = row_ptr[i], end = row_ptr[i + 1];
    for (int e = beg; e < end; e++) {
        int s = csr_src[e];
        const float4 v = *(const float4*)&t[(size_t)s * HID + l];
        acc.x += v.x; acc.y += v.y; acc.z += v.z; acc.w += v.w;
    }
    float di = dinv[i];
    float4 r;
    r.x = fmaxf(fmaf(acc.x, di, b[l + 0]), 0.f);
    r.y = fmaxf(fmaf(acc.y, di, b[l + 1]), 0.f);
    r.z = fmaxf(fmaf(acc.z, di, b[l + 2]), 0.f);
    r.w = fmaxf(fmaf(acc.w, di, b[l + 3]), 0.f);
    *(float4*)&hout[(size_t)i * HID + l] = r;
}

// ---------------- pooling v2: register-segment accumulate -> LDS bins -> few global atomics ----
__global__ void k_pool2(const float* __restrict__ h, const int* __restrict__ batch,
                        float* __restrict__ gsum, float* __restrict__ gcnt) {
    __shared__ float lacc[POOL_GSPAN][HID];
    __shared__ float lcnt[POOL_GSPAN];
    __shared__ int s_gmin;
    const int chunk_start = blockIdx.x * POOL_CHUNK;

    for (int j = threadIdx.x; j < POOL_GSPAN * HID; j += 256) ((float*)lacc)[j] = 0.f;
    if (threadIdx.x < POOL_GSPAN) lcnt[threadIdx.x] = 0.f;
    if (threadIdx.x == 0) {
        int cs = chunk_start < NN ? chunk_start : NN - 1;
        s_gmin = batch[cs];
    }
    __syncthreads();
    const int gmin = s_gmin;

    const int seg = threadIdx.x >> 3;            // 0..31
    const int l = (threadIdx.x & 7) * 4;         // feature quad
    const int i0 = chunk_start + seg * POOL_SEG;

    float4 acc = {0.f, 0.f, 0.f, 0.f};
    float cnt = 0.f;
    int cur_g = -1;

    for (int k = 0; k < POOL_SEG; k++) {
        int i = i0 + k;
        if (i >= NN) break;
        int g = batch[i];
        if (g != cur_g) {
            if (cur_g >= 0) {
                int bin = cur_g - gmin;
                if (bin >= 0 && bin < POOL_GSPAN) {
                    atomicAdd(&lacc[bin][l + 0], acc.x);
                    atomicAdd(&lacc[bin][l + 1], acc.y);
                    atomicAdd(&lacc[bin][l + 2], acc.z);
                    atomicAdd(&lacc[bin][l + 3], acc.w);
                    if (l == 0) atomicAdd(&lcnt[bin], cnt);
                } else {
                    atomicAdd(&gsum[cur_g * HID + l + 0], acc.x);
                    atomicAdd(&gsum[cur_g * HID + l + 1], acc.y);
                    atomicAdd(&gsum[cur_g * HID + l + 2], acc.z);
                    atomicAdd(&gsum[cur_g * HID + l + 3], acc.w);
                    if (l == 0) atomicAdd(&gcnt[cur_g], cnt);
                }
            }
            cur_g = g;
            acc.x = acc.y = acc.z = acc.w = 0.f;
            cnt = 0.f;
        }
        const float4 v = *(const float4*)&h[(size_t)i * HID + l];
        acc.x += v.x; acc.y += v.y; acc.z += v.z; acc.w += v.w;
        cnt += 1.f;
    }
    if (cur_g >= 0) {
        int bin = cur_g - gmin;
        if (bin >= 0 && bin < POOL_GSPAN) {
            atomicAdd(&lacc[bin][l + 0], acc.x);
            atomicAdd(&lacc[bin][l + 1], acc.y);
            atomicAdd(&lacc[bin][l + 2], acc.z);
            atomicAdd(&lacc[bin][l + 3], acc.w);
            if (l == 0) atomicAdd(&lcnt[bin], cnt);
        } else {
            atomicAdd(&gsum[cur_g * HID + l + 0], acc.x);
            atomicAdd(&gsum[cur_g * HID + l + 1], acc.y);
            atomicAdd(&gsum[cur_g * HID + l + 2], acc.z);
            atomicAdd(&gsum[cur_g * HID + l + 3], acc.w);
            if (l == 0) atomicAdd(&gcnt[cur_g], cnt);
        }
    }
    __syncthreads();

    // drain LDS bins: one atomic per touched (graph, feature)
    for (int j = threadIdx.x; j < POOL_GSPAN * HID; j += 256) {
        int bin = j / HID, f = j % HID;
        int g = gmin + bin;
        float v = lacc[bin][f];
        if (g < NG && v != 0.f) atomicAdd(&gsum[g * HID + f], v);
    }
    if (threadIdx.x < POOL_GSPAN) {
        int g = gmin + threadIdx.x;
        float c = lcnt[threadIdx.x];
        if (g < NG && c != 0.f) atomicAdd(&gcnt[g], c);
    }
}

// ---------------- classifier + log_softmax ----------------
__global__ void k_classify(const float* __restrict__ gsum, const float* __restrict__ gcnt,
                           const float* __restrict__ Wl, const float* __restrict__ bl,
                           float* __restrict__ out) {
    __shared__ float w[HID * NCLS];
    __shared__ float bb[NCLS];
    int t = threadIdx.x;
    for (int j = t; j < HID * NCLS; j += blockDim.x) w[j] = Wl[j];
    if (t < NCLS) bb[t] = bl[t];
    __syncthreads();
    if (t >= NG) return;
    float c = gcnt[t];
    c = c > 1.f ? c : 1.f;
    float p[HID];
#pragma unroll
    for (int k = 0; k < HID; k++) p[k] = gsum[t * HID + k] / c;
    float lg[NCLS];
    float m = -1e30f;
#pragma unroll
    for (int c2 = 0; c2 < NCLS; c2++) {
        float a = bb[c2];
#pragma unroll
        for (int k = 0; k < HID; k++) a = fmaf(p[k], w[k * NCLS + c2], a);
        a = a > 0.f ? a : 0.f;
        lg[c2] = a;
        m = fmaxf(m, a);
    }
    float s = 0.f;
#pragma unroll
    for (int c2 = 0; c2 < NCLS; c2++) s += expf(lg[c2] - m);
    float ls = logf(s);
#pragma unroll
    for (int c2 = 0; c2 < NCLS; c2++) out[t * NCLS + c2] = lg[c2] - m - ls;
}

extern "C" void kernel_launch(void* const* d_in, const int* in_sizes, int n_in,
                              void* d_out, int out_size, void* d_ws, size_t ws_size,
                              hipStream_t stream) {
    const float* x  = (const float*)d_in[0];
    const int* ei   = (const int*)d_in[1];      // [2, E] int32
    const int* batch = (const int*)d_in[2];
    const float* W0 = (const float*)d_in[3];
    const float* b0 = (const float*)d_in[4];
    const float* W1 = (const float*)d_in[5];
    const float* b1 = (const float*)d_in[6];
    const float* W2 = (const float*)d_in[7];
    const float* b2 = (const float*)d_in[8];
    const float* Wl = (const float*)d_in[9];
    const float* bl = (const float*)d_in[10];
    float* out = (float*)d_out;

    const int* esrc = ei;
    const int* edst = ei + NE;

    // bump allocator over workspace
    char* ws = (char*)d_ws;
    size_t off = 0;
    auto alloc = [&](size_t bytes) -> void* {
        void* p = ws + off;
        off = (off + bytes + 511) & ~(size_t)511;
        return p;
    };
    int*   counts  = (int*)alloc(NN * sizeof(int));
    int*   row_ptr = (int*)alloc((NN + 1) * sizeof(int));
    int*   cursor  = (int*)alloc(NN * sizeof(int));
    float* dinv    = (float*)alloc(NN * sizeof(float));
    int*   bsum    = (int*)alloc(256 * sizeof(int));
    int*   csr_src = (int*)alloc(NE * sizeof(int));
    float* tbuf    = (float*)alloc((size_t)NN * HID * sizeof(float));
    float* hA      = (float*)alloc((size_t)NN * HID * sizeof(float));
    float* hB      = (float*)alloc((size_t)NN * HID * sizeof(float));
    float* gsum    = (float*)alloc(NG * HID * sizeof(float));
    float* gcnt    = (float*)alloc(NG * sizeof(float));
    (void)ws_size; (void)in_sizes; (void)n_in; (void)out_size;

    // ---- CSR build ----
    k_init<<<256, 256, 0, stream>>>(counts, gsum, gcnt);
    k_hist<<<2048, 256, 0, stream>>>(edst, counts);
    k_dinv<<<(NN + 255) / 256, 256, 0, stream>>>(counts, dinv);
    k_scanA<<<NB, SCAN_B, 0, stream>>>(counts, row_ptr, bsum);
    k_scanB<<<1, 128, 0, stream>>>(bsum);
    k_scanC<<<NB, SCAN_B, 0, stream>>>(row_ptr, cursor, bsum);
    k_scatter<<<2048, 256, 0, stream>>>(esrc, edst, cursor, csr_src);

    const int gemm0_grid = (NN * HID + 255) / 256;
    const int agg_grid = (NN * 8 + 255) / 256;

    // ---- layer 0 ----
    k_gemm0<<<gemm0_grid, 256, 0, stream>>>(x, W0, dinv, tbuf);
    k_agg<<<agg_grid, 256, 0, stream>>>(tbuf, row_ptr, csr_src, dinv, b0, hA);
    // ---- layer 1 ----
    k_gemmh<<<gemm0_grid, 256, 0, stream>>>(hA, W1, dinv, tbuf);
    k_agg<<<agg_grid, 256, 0, stream>>>(tbuf, row_ptr, csr_src, dinv, b1, hB);
    // ---- layer 2 ----
    k_gemmh<<<gemm0_grid, 256, 0, stream>>>(hB, W2, dinv, tbuf);
    k_agg<<<agg_grid, 256, 0, stream>>>(tbuf, row_ptr, csr_src, dinv, b2, hA);

    // ---- pooling + classifier ----
    k_pool2<<<POOL_GRID, 256, 0, stream>>>(hA, batch, gsum, gcnt);
    k_classify<<<1, 128, 0, stream>>>(gsum, gcnt, Wl, bl, out);
}